// Round 1
// baseline (829.345 us; speedup 1.0000x reference)
//
#include <hip/hip_runtime.h>

typedef unsigned short u16;
typedef __attribute__((ext_vector_type(8))) short bf16x8;   // 8 bf16 (4 VGPRs)
typedef __attribute__((ext_vector_type(4))) float f32x4;

#define D_EMB 1024
#define NBAT  256
#define AS1 __attribute__((address_space(1)))
#define AS3 __attribute__((address_space(3)))

__device__ __forceinline__ u16 f2bf(float f){
    unsigned int u = __float_as_uint(f);
    unsigned int r = (u + 0x7fffu + ((u >> 16) & 1u)) >> 16;  // RNE
    return (u16)r;
}
__device__ __forceinline__ float leaky(float x){ return x > 0.f ? x : 0.1f * x; }

// truncation-pack two fp32 into 2 bf16 (memory order: a = low u16, b = high u16)
__device__ __forceinline__ unsigned pack2(float a, float b){
    return (__float_as_uint(a) >> 16) | (__float_as_uint(b) & 0xffff0000u);
}

// ---------------------------------------------------------------------------
// Pack img_emb(+pool_img as row 36) and cap_emb(+pool_txt as row 40) to bf16.
// imgw: [256][37][1024] bf16, capw: [256][41][1024] bf16
// ---------------------------------------------------------------------------
__global__ void pack_kernel(const float* __restrict__ pool_img, const float* __restrict__ img_emb,
                            const float* __restrict__ pool_txt, const float* __restrict__ cap_emb,
                            u16* __restrict__ imgw, u16* __restrict__ capw){
    int row = blockIdx.x;            // 0..19967
    const float* src; u16* dst;
    if (row < NBAT * 37){
        int e = row / 37, rr = row - e * 37;
        src = (rr < 36) ? (img_emb + ((size_t)e * 36 + rr) * D_EMB) : (pool_img + (size_t)e * D_EMB);
        dst = imgw + (size_t)row * D_EMB;
    } else {
        int r2 = row - NBAT * 37;
        int e = r2 / 41, rr = r2 - e * 41;
        src = (rr < 40) ? (cap_emb + ((size_t)e * 40 + rr) * D_EMB) : (pool_txt + (size_t)e * D_EMB);
        dst = capw + (size_t)r2 * D_EMB;
    }
    int t = threadIdx.x;             // 256 threads, 4 floats each
    float4 v = ((const float4*)src)[t];
    unsigned long long pk = (unsigned long long)f2bf(v.x)
        | ((unsigned long long)f2bf(v.y) << 16)
        | ((unsigned long long)f2bf(v.z) << 32)
        | ((unsigned long long)f2bf(v.w) << 48);
    *(unsigned long long*)(dst + (size_t)t * 4) = pk;
}

// ---------------------------------------------------------------------------
// Pool-vector norms
// ---------------------------------------------------------------------------
__global__ void norm_kernel(const float* __restrict__ pool_img, const float* __restrict__ pool_txt,
                            float* __restrict__ w1i, float* __restrict__ w1t){
    __shared__ float red[256];
    int v = blockIdx.x;              // 0..511
    const float* src = (v < 256) ? (pool_img + (size_t)v * D_EMB)
                                 : (pool_txt + (size_t)(v - 256) * D_EMB);
    int t = threadIdx.x;
    float4 x = ((const float4*)src)[t];
    red[t] = x.x*x.x + x.y*x.y + x.z*x.z + x.w*x.w;
    __syncthreads();
    for (int off = 128; off > 0; off >>= 1){
        if (t < off) red[t] += red[t + off];
        __syncthreads();
    }
    if (t == 0){
        float n = sqrtf(red[0]);
        if (v < 256) w1i[v] = n; else w1t[v - 256] = n;
    }
}

// ---------------------------------------------------------------------------
// MFMA Gram kernel (reads packed bf16): blk<256 -> G[b]=E_img E_img^T (R=36),
// else H[b]=E_cap E_cap^T (R=40). Frag-order staging via global_load_lds.
// ---------------------------------------------------------------------------
__launch_bounds__(256, 2)
__global__ void gram_kernel(const u16* __restrict__ imgw, const u16* __restrict__ capw,
                            float* __restrict__ G, float* __restrict__ H){
    __shared__ __align__(16) char gsm[6144];    // 3 tiles x 2 kk x 64 lanes x 16B
    int blk = blockIdx.x;
    int tid = threadIdx.x, lane = tid & 63;
    int wave = __builtin_amdgcn_readfirstlane(tid >> 6);
    int frow = lane & 15, q = lane >> 4;

    const u16* E; float* Gout; int R;
    if (blk < NBAT){ E = imgw + (size_t)blk * 37 * D_EMB; Gout = G + (size_t)blk * 1296; R = 36; }
    else { int b = blk - NBAT; E = capw + (size_t)b * 41 * D_EMB; Gout = H + (size_t)b * 1600; R = 40; }

    {   // zero staging once (pad rows stay zero)
        uint4 z = {0u,0u,0u,0u};
        for (int off = tid * 16; off < 6144; off += 4096) *(uint4*)(gsm + off) = z;
    }

    // staging groups g = kk*3 + t, g in [0,6)
    const u16* gsrc[2]; int goff[2]; bool gval[2];
    #pragma unroll
    for (int j = 0; j < 2; ++j){
        int g = wave + j * 4;
        gval[j] = false; gsrc[j] = E; goff[j] = 0;
        if (g < 6){
            int kk = g / 3, t = g - kk * 3;
            int row = t * 16 + frow;
            gsrc[j] = E + (size_t)row * D_EMB + kk * 32 + q * 8;
            goff[j] = g * 1024;
            gval[j] = (row < R);
        }
    }

    int wm = wave >> 1, wn = wave & 1;
    int nTm = wm ? 1 : 2, nTn = wn ? 1 : 2;
    f32x4 acc[2][2];
    #pragma unroll
    for (int a = 0; a < 2; ++a)
        #pragma unroll
        for (int b = 0; b < 2; ++b) acc[a][b] = (f32x4){0.f,0.f,0.f,0.f};

    for (int c = 0; c < 16; ++c){
        __syncthreads();
        #pragma unroll
        for (int j = 0; j < 2; ++j){
            if (gval[j]){
                __builtin_amdgcn_global_load_lds(
                    (const AS1 void*)(const void*)(gsrc[j] + c * 64),
                    (AS3 void*)(void*)(gsm + goff[j] + lane * 16),
                    16, 0, 0);
            }
        }
        __syncthreads();
        #pragma unroll
        for (int kk = 0; kk < 2; ++kk){
            bf16x8 fA[2], fB[2];
            #pragma unroll
            for (int mi = 0; mi < 2; ++mi)
                if (mi < nTm) fA[mi] = *(const bf16x8*)(gsm + ((kk * 3 + (wm + mi * 2)) * 64 + lane) * 16);
            #pragma unroll
            for (int ni = 0; ni < 2; ++ni)
                if (ni < nTn) fB[ni] = *(const bf16x8*)(gsm + ((kk * 3 + (wn + ni * 2)) * 64 + lane) * 16);
            #pragma unroll
            for (int mi = 0; mi < 2; ++mi)
                if (mi < nTm)
                    #pragma unroll
                    for (int ni = 0; ni < 2; ++ni)
                        if (ni < nTn)
                            acc[mi][ni] = __builtin_amdgcn_mfma_f32_16x16x32_bf16(
                                fA[mi], fB[ni], acc[mi][ni], 0, 0, 0);
        }
    }

    #pragma unroll
    for (int mi = 0; mi < 2; ++mi){
        if (mi < nTm){
            int tm = wm + mi * 2;
            #pragma unroll
            for (int ni = 0; ni < 2; ++ni){
                if (ni < nTn){
                    int tn = wn + ni * 2;
                    int col = tn * 16 + frow;
                    if (col < R){
                        #pragma unroll
                        for (int g = 0; g < 4; ++g){
                            int row = tm * 16 + q * 4 + g;
                            if (row < R) Gout[row * R + col] = acc[mi][ni][g];
                        }
                    }
                }
            }
        }
    }
}

// ---------------------------------------------------------------------------
// Cholesky kernel: per matrix, G = L·L^T (fp32), store L^T rows as bf16 in
// [48][64] zero-padded layout: Lb[n][k] = L[k][n]. One wave per matrix,
// lane = row, fully unrolled left-looking factorization via readlane shfl.
// Random-normal embeddings make G/H strongly PD (eig ~ 1024(1±0.4)), so no
// pivoting issues; a <=0 pivot zeroes its column (rank-deficient fallback).
// ---------------------------------------------------------------------------
template<int R>
__device__ __forceinline__ void chol_wave(const float* __restrict__ src,
                                          u16* __restrict__ dst, int lane){
    int r = lane;
    bool act = (r < R);
    const float* row = src + (size_t)(act ? r : 0) * R;
    float a[R];
    #pragma unroll
    for (int k = 0; k < R; ++k) a[k] = act ? row[k] : 0.f;
    #pragma unroll
    for (int j = 0; j < R; ++j){
        float ajj = __shfl(a[j], j);
        float inv = (ajj > 1e-12f) ? rsqrtf(ajj) : 0.f;
        float lrj = a[j] * inv;
        if (r < j || !act) lrj = 0.f;           // strict lower + diag only
        dst[j * 64 + lane] = f2bf(lrj);         // row j of Lb = column j of L
        #pragma unroll
        for (int k = j + 1; k < R; ++k){
            float lkj = __shfl(lrj, k);
            a[k] = fmaf(-lrj, lkj, a[k]);
        }
    }
    #pragma unroll
    for (int j = R; j < 48; ++j) dst[j * 64 + lane] = 0;   // zero pad rows
}

__global__ void chol_kernel(const float* __restrict__ G, const float* __restrict__ H,
                            u16* __restrict__ Lbi, u16* __restrict__ Lbc){
    int lane = threadIdx.x & 63;
    int wave = threadIdx.x >> 6;
    int id = blockIdx.x * 4 + wave;   // 0..511 (uniform branch per block)
    if (id < NBAT) chol_wave<36>(G + (size_t)id * 1296, Lbi + (size_t)id * 3072, lane);
    else           chol_wave<40>(H + (size_t)(id - NBAT) * 1600, Lbc + (size_t)(id - NBAT) * 3072, lane);
}

// ---------------------------------------------------------------------------
// Fused main kernel. One block = 2 images x 2 captions.
// GEMM phase unchanged. Post phase reworked: the O(R^2)/O(L^2) scalar
// quadratic forms u^T G u / v^T H v are replaced by per-wave MFMA against the
// Cholesky factors:  zz[l] = ||U·L||^2 row-wise  (18 mfma per side), with the
// contraction done by squaring accumulator registers + shfl_xor reduce.
// Softmax weights (already bf16-packed in regs) are staged into the dead Call
// LDS region (per-wave 6144B slice, slot-XOR swizzle) in A-frag layout; L
// fragments come straight from global (6KB/matrix, L1/L2 resident).
// bounds (256,4): u[18]+v[20] live across the overlay barrier + 36-reg acc
// need ~100 arch VGPRs; (256,5)'s ~96 budget would spill.
// ---------------------------------------------------------------------------
__launch_bounds__(256, 4)
__global__ void fused_kernel(const u16* __restrict__ imgw, const u16* __restrict__ capw,
                             const u16* __restrict__ Lbi, const u16* __restrict__ Lbc,
                             const float* __restrict__ w1i, const float* __restrict__ w1t,
                             float* __restrict__ out){
    __shared__ __align__(16) char smem[26624];
    float* Call = (float*)smem;                 // overlay after GEMM: [74][85]
    float* rnb  = (float*)(smem + 25160);       // [4][36]
    float* cnb  = (float*)(smem + 25736);       // [4][40]

    int tid  = threadIdx.x;
    int lane = tid & 63;
    int wave = __builtin_amdgcn_readfirstlane(tid >> 6);
    int frow = lane & 15, q = lane >> 4;

    int lin = blockIdx.x;
    int xcd = lin & 7;                   // XCD-aware swizzle
    int s   = lin >> 3;                  // 0..2047
    int b_t = (xcd << 4) | (s & 15);     // each XCD owns 16 b-tiles
    int i_t = s >> 4;                    // 0..127
    int b0 = b_t * 2, i0 = i_t * 2;
    const u16* Ag = imgw + (size_t)b0 * 37 * D_EMB;   // 74 rows
    const u16* Bg = capw + (size_t)i0 * 41 * D_EMB;   // 82 rows

    {   // zero staging region once (pad slots stay zero forever)
        uint4 z = {0u,0u,0u,0u};
        for (int off = tid * 16; off < 22528; off += 4096) *(uint4*)(smem + off) = z;
    }

    // staging groups: A g in [0,10): tm=g%5, kk=g/5, off g*1024
    //                 B g in [10,22): gb=g-10, tn=gb%6, kk=gb/6, off 10240+gb*1024
    const u16* gsrc[6]; int goff[6]; bool gval[6];
    #pragma unroll
    for (int j = 0; j < 6; ++j){
        int g = wave + j * 4;
        gval[j] = false; gsrc[j] = Ag; goff[j] = 0;
        if (g < 22){
            if (g < 10){
                int tm = g % 5, kk = g / 5;
                int row = tm * 16 + frow;
                gsrc[j] = Ag + (size_t)row * D_EMB + kk * 32 + q * 8;
                goff[j] = g * 1024;
                gval[j] = (row < 74);
            } else {
                int gb = g - 10;
                int tn = gb % 6, kk = gb / 6;
                int row = tn * 16 + frow;
                gsrc[j] = Bg + (size_t)row * D_EMB + kk * 32 + q * 8;
                goff[j] = 10240 + gb * 1024;
                gval[j] = (row < 82);
            }
        }
    }

    int wm = wave >> 1, wn = wave & 1;     // 2x2 wave grid over 5x6 MFMA tiles
    int nTm = wm ? 2 : 3;                  // m-tiles {wm, wm+2, wm+4} < 5
    f32x4 acc[3][3];
    #pragma unroll
    for (int aa = 0; aa < 3; ++aa)
        #pragma unroll
        for (int bb = 0; bb < 3; ++bb) acc[aa][bb] = (f32x4){0.f, 0.f, 0.f, 0.f};

    for (int c = 0; c < 16; ++c){          // K chunks of 64
        __syncthreads();                   // prev chunk's frag reads done
        #pragma unroll
        for (int j = 0; j < 6; ++j){
            if (gval[j]){
                __builtin_amdgcn_global_load_lds(
                    (const AS1 void*)(const void*)(gsrc[j] + c * 64),
                    (AS3 void*)(void*)(smem + goff[j] + lane * 16),
                    16, 0, 0);
            }
        }
        __syncthreads();                   // drains vmcnt -> data in LDS
        #pragma unroll
        for (int kk = 0; kk < 2; ++kk){
            bf16x8 bfr[3];
            #pragma unroll
            for (int ni = 0; ni < 3; ++ni){
                int tn = wn + ni * 2;
                bfr[ni] = *(const bf16x8*)(smem + 10240 + ((kk * 6 + tn) * 64 + lane) * 16);
            }
            #pragma unroll
            for (int mi = 0; mi < 3; ++mi){
                if (mi < nTm){
                    int tm = wm + mi * 2;
                    bf16x8 af = *(const bf16x8*)(smem + ((kk * 5 + tm) * 64 + lane) * 16);
                    #pragma unroll
                    for (int ni = 0; ni < 3; ++ni){
                        acc[mi][ni] = __builtin_amdgcn_mfma_f32_16x16x32_bf16(
                            af, bfr[ni], acc[mi][ni], 0, 0, 0);
                    }
                }
            }
        }
    }
    __syncthreads();                       // all frag reads done before overlay

    // C/D layout: col = lane&15 (B-row), row = (lane>>4)*4 + reg (A-row)
    #pragma unroll
    for (int mi = 0; mi < 3; ++mi){
        if (mi < nTm){
            int tm = wm + mi * 2;
            #pragma unroll
            for (int ni = 0; ni < 3; ++ni){
                int tn = wn + ni * 2;
                int col = tn * 16 + frow;
                int rbase = tm * 16 + q * 4;
                if (col < 82){
                    #pragma unroll
                    for (int g = 0; g < 4; ++g){
                        int rowc = rbase + g;
                        if (rowc < 74) Call[rowc * 85 + col] = acc[mi][ni][g];
                    }
                }
            }
        }
    }
    __syncthreads();

    // ----- post-processing: one wave per (b,i) pair -----
    int pb = wave >> 1, pi = wave & 1;
    int bg = b0 + pb, ig = i0 + pi;
    const float* Sv = Call + (pb * 37) * 85 + pi * 41;  // S[r*85+l]; p[r]=S[r*85+40]; qv[l]=S[36*85+l]
    const u16* Lb_t2i = Lbi + (size_t)bg * 3072;        // [48][64] bf16, B[n][k]=L[k][n]
    const u16* Lb_i2t = Lbc + (size_t)ig * 3072;

    {   // row norms over words (lanes = regions)
        int r0 = (lane < 36) ? lane : 35;
        float s2 = 0.f;
        #pragma unroll
        for (int l = 0; l < 40; ++l){ float x = leaky(Sv[r0 * 85 + l]); s2 = fmaf(x, x, s2); }
        if (lane < 36) rnb[wave * 36 + lane] = 1.f / (sqrtf(s2) + 1e-8f);
    }
    {   // column norms over regions (lanes = words)
        int l0 = (lane < 40) ? lane : 39;
        float s2 = 0.f;
        #pragma unroll
        for (int r = 0; r < 36; ++r){ float x = leaky(Sv[r * 85 + l0]); s2 = fmaf(x, x, s2); }
        if (lane < 40) cnb[wave * 40 + lane] = 1.f / (sqrtf(s2) + 1e-8f);
    }

    // softmax weights u (lanes = words) + t2i numerator (dd cancels in sim)
    unsigned up[18]; float num1 = 0.f;
    {
        int lc = (lane < 40) ? lane : 39;
        #pragma unroll
        for (int r = 0; r < 36; r += 2){
            float x0 = leaky(Sv[r * 85 + lc]) * rnb[wave * 36 + r];
            float x1 = leaky(Sv[(r + 1) * 85 + lc]) * rnb[wave * 36 + r + 1];
            float e0 = __expf(9.0f * x0), e1 = __expf(9.0f * x1);
            num1 = fmaf(e0, Sv[r * 85 + 40], fmaf(e1, Sv[(r + 1) * 85 + 40], num1));
            up[r >> 1] = pack2(e0, e1);
        }
    }
    // softmax weights v (lanes = regions) + i2t numerator
    unsigned vp[20]; float num2 = 0.f;
    {
        int rc = (lane < 36) ? lane : 35;
        #pragma unroll
        for (int l = 0; l < 40; l += 2){
            float x0 = leaky(Sv[rc * 85 + l]) * cnb[wave * 40 + l];
            float x1 = leaky(Sv[rc * 85 + l + 1]) * cnb[wave * 40 + l + 1];
            float e0 = __expf(9.0f * x0), e1 = __expf(9.0f * x1);
            num2 = fmaf(e0, Sv[36 * 85 + l], fmaf(e1, Sv[36 * 85 + l + 1], num2));
            vp[l >> 1] = pack2(e0, e1);
        }
    }
    float base = Sv[36 * 85 + 40];
    __syncthreads();        // S fully consumed; Call region becomes frag staging

    // per-wave staging slice: [48 rows][128 B] with slot-XOR swizzle
    // (slot' = slot ^ (row&7)) so A-frag ds_read_b128 spreads across banks.
    char* slice = smem + wave * 6144;
    int sxw = lane & 7;

    // ---- t2i:  Y = U·L_img  (M=40 words, N=36, K=36 pad 64) ----
    if (lane < 40){
        char* rp = slice + lane * 128;
        #pragma unroll
        for (int jj = 0; jj < 9; ++jj){                 // cols 0..35 (bf16 pairs)
            int slot = jj >> 1, wi = (jj & 1) * 8;
            uint2 w; w.x = up[jj * 2]; w.y = up[jj * 2 + 1];
            *(uint2*)(rp + ((slot ^ sxw) * 16 + wi)) = w;
        }
        uint2 z2; z2.x = 0u; z2.y = 0u;
        *(uint2*)(rp + ((4 ^ sxw) * 16 + 8)) = z2;      // cols 36..39 = 0
        uint4 z4 = {0u,0u,0u,0u};
        #pragma unroll
        for (int slot = 5; slot < 8; ++slot)            // cols 40..63 = 0
            *(uint4*)(rp + ((slot ^ sxw) * 16)) = z4;
    }

    float tsum;
    {
        f32x4 pacc[3][3];
        #pragma unroll
        for (int aa = 0; aa < 3; ++aa)
            #pragma unroll
            for (int bb = 0; bb < 3; ++bb) pacc[aa][bb] = (f32x4){0.f,0.f,0.f,0.f};
        #pragma unroll
        for (int kk = 0; kk < 2; ++kk){
            bf16x8 afr[3];
            #pragma unroll
            for (int mt = 0; mt < 3; ++mt){
                int row = mt * 16 + frow;
                afr[mt] = *(const bf16x8*)(slice + row * 128 + (((kk * 4 + q) ^ (row & 7)) * 16));
            }
            #pragma unroll
            for (int nt = 0; nt < 3; ++nt){
                bf16x8 bfr = *(const bf16x8*)(Lb_t2i + (nt * 16 + frow) * 64 + kk * 32 + q * 8);
                #pragma unroll
                for (int mt = 0; mt < 3; ++mt)
                    pacc[mt][nt] = __builtin_amdgcn_mfma_f32_16x16x32_bf16(
                        afr[mt], bfr, pacc[mt][nt], 0, 0, 0);
            }
        }
        // zz[m] = sum_n Y[m][n]^2 ; D layout: (m = 16mt+4q+g, n = 16nt+frow)
        float w1 = w1t[ig];
        tsum = 0.f;
        #pragma unroll
        for (int mt = 0; mt < 3; ++mt){
            #pragma unroll
            for (int g = 0; g < 4; ++g){
                float sv = pacc[mt][0][g] * pacc[mt][0][g]
                         + pacc[mt][1][g] * pacc[mt][1][g];
                float t2 = pacc[mt][2][g] * pacc[mt][2][g];
                sv += (frow < 4) ? t2 : 0.f;            // n = 32+frow < 36
                sv += __shfl_xor(sv, 1); sv += __shfl_xor(sv, 2);
                sv += __shfl_xor(sv, 4); sv += __shfl_xor(sv, 8);
                int m = mt * 16 + 4 * q + g;
                float nm = __shfl(num1, m);
                float sim = nm / fmaxf(w1 * sqrtf(sv), 1e-8f);
                tsum += (m < 40) ? sim : 0.f;           // mask garbage words
            }
        }
        tsum += __shfl_xor(tsum, 16);
        tsum += __shfl_xor(tsum, 32);
    }

    // ---- i2t:  Y = V·L_cap  (M=36 regions, N=40, K=40 pad 64) ----
    if (lane < 36){
        char* rp = slice + lane * 128;
        #pragma unroll
        for (int jj = 0; jj < 10; ++jj){                // cols 0..39
            int slot = jj >> 1, wi = (jj & 1) * 8;
            uint2 w; w.x = vp[jj * 2]; w.y = vp[jj * 2 + 1];
            *(uint2*)(rp + ((slot ^ sxw) * 16 + wi)) = w;
        }
        uint4 z4 = {0u,0u,0u,0u};
        #pragma unroll
        for (int slot = 5; slot < 8; ++slot)            // cols 40..63 = 0
            *(uint4*)(rp + ((slot ^ sxw) * 16)) = z4;
    }

    float isum;
    {
        f32x4 pacc[3][3];
        #pragma unroll
        for (int aa = 0; aa < 3; ++aa)
            #pragma unroll
            for (int bb = 0; bb < 3; ++bb) pacc[aa][bb] = (f32x4){0.f,0.f,0.f,0.f};
        #pragma unroll
        for (int kk = 0; kk < 2; ++kk){
            bf16x8 afr[3];
            #pragma unroll
            for (int mt = 0; mt < 3; ++mt){
                int row = mt * 16 + frow;
                afr[mt] = *(const bf16x8*)(slice + row * 128 + (((kk * 4 + q) ^ (row & 7)) * 16));
            }
            #pragma unroll
            for (int nt = 0; nt < 3; ++nt){
                bf16x8 bfr = *(const bf16x8*)(Lb_i2t + (nt * 16 + frow) * 64 + kk * 32 + q * 8);
                #pragma unroll
                for (int mt = 0; mt < 3; ++mt)
                    pacc[mt][nt] = __builtin_amdgcn_mfma_f32_16x16x32_bf16(
                        afr[mt], bfr, pacc[mt][nt], 0, 0, 0);
            }
        }
        float w1 = w1i[bg];
        isum = 0.f;
        #pragma unroll
        for (int mt = 0; mt < 3; ++mt){
            #pragma unroll
            for (int g = 0; g < 4; ++g){
                float sv = pacc[mt][0][g] * pacc[mt][0][g]
                         + pacc[mt][1][g] * pacc[mt][1][g];
                float t2 = pacc[mt][2][g] * pacc[mt][2][g];
                sv += (frow < 8) ? t2 : 0.f;            // n = 32+frow < 40
                sv += __shfl_xor(sv, 1); sv += __shfl_xor(sv, 2);
                sv += __shfl_xor(sv, 4); sv += __shfl_xor(sv, 8);
                int m = mt * 16 + 4 * q + g;
                float nm = __shfl(num2, m);
                float sim = nm / fmaxf(w1 * sqrtf(sv), 1e-8f);
                isum += (m < 36) ? sim : 0.f;           // mask garbage regions
            }
        }
        isum += __shfl_xor(isum, 16);
        isum += __shfl_xor(isum, 32);
    }

    if (lane == 0)
        out[bg * 256 + ig] = tsum * (1.f / 40.f) + isum * (1.f / 36.f) + base;
}

// ---------------------------------------------------------------------------
extern "C" void kernel_launch(void* const* d_in, const int* in_sizes, int n_in,
                              void* d_out, int out_size, void* d_ws, size_t ws_size,
                              hipStream_t stream){
    const float* pool_img = (const float*)d_in[0];
    const float* img_emb  = (const float*)d_in[1];
    const float* pool_txt = (const float*)d_in[2];
    const float* cap_emb  = (const float*)d_in[3];
    float* out = (float*)d_out;

    char* ws = (char*)d_ws;                         // needs ~47 MB
    size_t o = 0;
    u16* imgw = (u16*)(ws + o);  o += (size_t)256 * 37 * 1024 * 2;
    u16* capw = (u16*)(ws + o);  o += (size_t)256 * 41 * 1024 * 2;
    float* G  = (float*)(ws + o); o += (size_t)256 * 36 * 36 * 4;
    float* H  = (float*)(ws + o); o += (size_t)256 * 40 * 40 * 4;
    float* w1i = (float*)(ws + o); o += 1024;
    float* w1t = (float*)(ws + o); o += 1024;
    u16* Lbi = (u16*)(ws + o); o += (size_t)256 * 48 * 64 * 2;   // chol(G)^T, bf16 [48][64]
    u16* Lbc = (u16*)(ws + o); o += (size_t)256 * 48 * 64 * 2;   // chol(H)^T

    pack_kernel<<<19968, 256, 0, stream>>>(pool_img, img_emb, pool_txt, cap_emb, imgw, capw);
    norm_kernel<<<512, 256, 0, stream>>>(pool_img, pool_txt, w1i, w1t);
    gram_kernel<<<512, 256, 0, stream>>>(imgw, capw, G, H);
    chol_kernel<<<128, 256, 0, stream>>>(G, H, Lbi, Lbc);
    fused_kernel<<<16384, 256, 0, stream>>>(imgw, capw, Lbi, Lbc, w1i, w1t, out);
}